// Round 2
// baseline (166.694 us; speedup 1.0000x reference)
//
#include <hip/hip_runtime.h>
#include <hip/hip_bf16.h>
#include <stdint.h>

#define BROWS 32768
#define LATENT 1024
#define HID 512

typedef float f32x4 __attribute__((ext_vector_type(4)));
typedef __bf16 bf16x8 __attribute__((ext_vector_type(8)));
typedef unsigned short us8 __attribute__((ext_vector_type(8)));

__device__ __forceinline__ void gload16(const void* g, void* l) {
  __builtin_amdgcn_global_load_lds(
      (__attribute__((address_space(1))) void*)g,
      (__attribute__((address_space(3))) void*)l, 16, 0, 0);
}

// hi/lo bf16 split: x ~= hi + lo, residual ~2^-17 * |x|
__device__ __forceinline__ void split_bf16(float x, unsigned short& hi, unsigned short& lo) {
  __bf16 h = (__bf16)x;
  float r = x - (float)h;
  __bf16 l = (__bf16)r;
  hi = __builtin_bit_cast(unsigned short, h);
  lo = __builtin_bit_cast(unsigned short, l);
}

__device__ __forceinline__ f32x4 mfma16(bf16x8 a, bf16x8 b, f32x4 c) {
  return __builtin_amdgcn_mfma_f32_16x16x32_bf16(a, b, c, 0, 0, 0);
}

__device__ __forceinline__ bf16x8 ldfrag(const void* p) {
  return __builtin_bit_cast(bf16x8, *(const us8*)p);
}

// ---------------- prep: W1 (1024x512 f32) -> W1T hi/lo bf16 [512][1024] ----------------
__global__ __launch_bounds__(256) void k_prep_w1t(const float* __restrict__ W1,
                                                  unsigned short* __restrict__ hi,
                                                  unsigned short* __restrict__ lo) {
  __shared__ float t[64][65];
  const int i = threadIdx.x;
  const int k0 = blockIdx.x * 64;  // over LATENT=1024 (16 blocks)
  const int n0 = blockIdx.y * 64;  // over HID=512    (8 blocks)
#pragma unroll
  for (int s = 0; s < 4; s++) {
    const int r = s * 16 + (i >> 4);
    const int c = (i & 15) * 4;
    float4 v = *(const float4*)&W1[(size_t)(k0 + r) * HID + n0 + c];
    t[r][c] = v.x; t[r][c + 1] = v.y; t[r][c + 2] = v.z; t[r][c + 3] = v.w;
  }
  __syncthreads();
#pragma unroll
  for (int s = 0; s < 4; s++) {
    const int n = s * 16 + (i >> 4);
    const int k = (i & 15) * 4;
    unsigned short h[4], l[4];
#pragma unroll
    for (int j = 0; j < 4; j++) split_bf16(t[k + j][n], h[j], l[j]);
    *(ushort4*)&hi[(size_t)(n0 + n) * LATENT + k0 + k] = make_ushort4(h[0], h[1], h[2], h[3]);
    *(ushort4*)&lo[(size_t)(n0 + n) * LATENT + k0 + k] = make_ushort4(l[0], l[1], l[2], l[3]);
  }
}

// ---------------- prep: W2 (512x92 f32) -> W2T hi/lo bf16 [128][512], rows>=92 zero ----
__global__ __launch_bounds__(256) void k_prep_w2t(const float* __restrict__ W2,
                                                  unsigned short* __restrict__ hi,
                                                  unsigned short* __restrict__ lo) {
  const int idx = blockIdx.x * 256 + threadIdx.x;  // 65536 = 128*512
  const int n = idx >> 9, k = idx & 511;
  const float v = (n < 92) ? W2[(size_t)k * 92 + n] : 0.0f;
  unsigned short h, l;
  split_bf16(v, h, l);
  hi[idx] = h;
  lo[idx] = l;
}

// ---------------- GEMM1: h = silu(z @ W1 + b1), phase-pipelined hi/lo ----------------
// 128x128 tile, BK=32, 3 phases/K-tile (HH, LH, HL), counted vmcnt, XOR-swizzled LDS.
__global__ __launch_bounds__(256, 2) void k_gemm1(
    const float* __restrict__ z, const unsigned short* __restrict__ w1h,
    const unsigned short* __restrict__ w1l, const float* __restrict__ b1,
    unsigned short* __restrict__ hh, unsigned short* __restrict__ hl) {
  // per-buf byte layout (32KB): Ah@0, Al@8192, Bh@16384, Bl@24576; 2 bufs = 64KB
  __shared__ __attribute__((aligned(16))) unsigned short lds_u[32768];
  char* lb = (char*)lds_u;

  const int tid = threadIdx.x;
  const int bid = blockIdx.x;
  const int swz = (bid & 7) * 128 + (bid >> 3);  // bijective XCD swizzle (1024 blocks)
  const int nb = swz >> 8;                       // 0..3  (128-block chunk shares B panel)
  const int mb = swz & 255;                      // 0..255
  const int m0 = mb * 128;
  const int n0g = nb * 128;

  const int wv = tid >> 6, l = tid & 63;
  const int l15 = l & 15, lg = l >> 4;

  // frag read byte offsets (same XOR swizzle for A and B regions, 64B rows)
  const int abase = l15 * 64 + ((lg ^ ((l15 >> 1) & 3)) << 4);

  // A reg-stage addressing: rows tid>>3 (+32i), 16B chunks
  const float* zbase = z + (size_t)(m0 + (tid >> 3)) * LATENT + (tid & 7) * 4;
  // A LDS write byte offset (swizzled), +i*2048 per row-group
  const int wbyte = (tid >> 3) * 64 + (((tid & 7) * 8) ^ (((tid >> 4) & 3) << 4));

  // B gload: per-lane pre-swizzled global source; linear LDS dest
  const size_t bsrc = (size_t)(n0g + 32 * wv + (l >> 2)) * LATENT +
                      ((((l & 3) ^ ((l >> 3) & 3))) << 3);

  f32x4 acc[8][2] = {};
  float4 zr[4];
  bf16x8 ah[8], bhf[2], blf[2];

#define AHO 0
#define ALO 8192
#define BHO 16384
#define BLO 24576

#define ISSUE_A(kt1)                                                         \
  {                                                                          \
    _Pragma("unroll") for (int i_ = 0; i_ < 4; i_++)                         \
        zr[i_] = *(const float4*)(zbase + (size_t)(32 * i_) * LATENT + (kt1) * 32); \
  }

#define ISSUE_B(arr, kt1, dstoff, j_)                                        \
  gload16(arr + bsrc + (size_t)(16 * (j_)) * LATENT + (kt1) * 32,            \
          lb + (dstoff) + (wv * 2 + (j_)) * 1024);

#define WRITE_A(dstAh, dstAl)                                                \
  {                                                                          \
    _Pragma("unroll") for (int i_ = 0; i_ < 4; i_++) {                       \
      unsigned short h0, h1, h2, h3, q0, q1, q2, q3;                         \
      split_bf16(zr[i_].x, h0, q0); split_bf16(zr[i_].y, h1, q1);            \
      split_bf16(zr[i_].z, h2, q2); split_bf16(zr[i_].w, h3, q3);            \
      *(ushort4*)(lb + (dstAh) + wbyte + i_ * 2048) = make_ushort4(h0, h1, h2, h3); \
      *(ushort4*)(lb + (dstAl) + wbyte + i_ * 2048) = make_ushort4(q0, q1, q2, q3); \
    }                                                                        \
  }

#define LD_AFRAGS(dst, roff)                                                 \
  {                                                                          \
    _Pragma("unroll") for (int mf = 0; mf < 8; mf++)                         \
        dst[mf] = ldfrag(lb + (roff) + abase + mf * 1024);                   \
  }

#define LD_BFRAGS(dst, roff)                                                 \
  {                                                                          \
    _Pragma("unroll") for (int nf = 0; nf < 2; nf++)                         \
        dst[nf] = ldfrag(lb + (roff) + wv * 2048 + nf * 1024 + abase);       \
  }

#define DO_MFMA(AF, BF)                                                      \
  {                                                                          \
    __builtin_amdgcn_s_setprio(1);                                           \
    _Pragma("unroll") for (int mf = 0; mf < 8; mf++)                         \
        _Pragma("unroll") for (int nf = 0; nf < 2; nf++)                     \
            acc[mf][nf] = mfma16(AF[mf], BF[nf], acc[mf][nf]);               \
    __builtin_amdgcn_s_setprio(0);                                           \
  }

#define SBAR  __builtin_amdgcn_s_barrier()
#define SCH0  __builtin_amdgcn_sched_barrier(0)

  // ---- prologue: stage tile 0 into buf 0 ----
  ISSUE_A(0);
  SCH0;
  ISSUE_B(w1h, 0, BHO, 0); ISSUE_B(w1h, 0, BHO, 1);
  ISSUE_B(w1l, 0, BLO, 0); ISSUE_B(w1l, 0, BLO, 1);
  SCH0;
  asm volatile("s_waitcnt vmcnt(4)" ::: "memory");   // A0 regs ready
  SCH0;
  WRITE_A(AHO, ALO);
  asm volatile("s_waitcnt lgkmcnt(0)" ::: "memory");
  SBAR; SCH0;

#pragma unroll 2
  for (int t = 0; t < 32; ++t) {
    const int cur = (t & 1) * 32768;
    const int nxt = cur ^ 32768;
    const bool last = (t == 31);

    // ---- phase 1: term Ah*Bh ----
    asm volatile("s_waitcnt vmcnt(1)" ::: "memory");  // Bh(t) landed
    SCH0;
    LD_AFRAGS(ah, cur + AHO);
    LD_BFRAGS(bhf, cur + BHO);
    if (!last) {
      ISSUE_A(t + 1);
      SCH0;
      ISSUE_B(w1h, t + 1, nxt + BHO, 0);
    }
    SBAR; SCH0;
    DO_MFMA(ah, bhf);
    SBAR; SCH0;

    // ---- phase 2: term Al*Bh ----
    {
      bf16x8 alf[8];
      LD_AFRAGS(alf, cur + ALO);
      if (!last) {
        ISSUE_B(w1h, t + 1, nxt + BHO, 1);
        ISSUE_B(w1l, t + 1, nxt + BLO, 0);
      }
      SBAR; SCH0;
      DO_MFMA(alf, bhf);
      SBAR; SCH0;
    }

    // ---- phase 3: term Ah*Bl ----
    if (!last) { asm volatile("s_waitcnt vmcnt(7)" ::: "memory"); }
    else       { asm volatile("s_waitcnt vmcnt(0)" ::: "memory"); }
    SCH0;
    LD_BFRAGS(blf, cur + BLO);
    if (!last) {
      ISSUE_B(w1l, t + 1, nxt + BLO, 1);
      asm volatile("s_waitcnt vmcnt(3)" ::: "memory");  // A(t+1) regs ready
      SCH0;
      WRITE_A(nxt + AHO, nxt + ALO);
      asm volatile("s_waitcnt lgkmcnt(0)" ::: "memory");
      SCH0;
    }
    SBAR; SCH0;
    DO_MFMA(ah, blf);
    SBAR; SCH0;
  }

  // ---- epilogue: bias + silu + hi/lo split store ----
  float b1v[2];
#pragma unroll
  for (int nf = 0; nf < 2; nf++) b1v[nf] = b1[n0g + wv * 32 + nf * 16 + l15];

#pragma unroll
  for (int mf = 0; mf < 8; mf++)
#pragma unroll
    for (int nf = 0; nf < 2; nf++)
#pragma unroll
      for (int r = 0; r < 4; r++) {
        const int gm = m0 + mf * 16 + (lg << 2) + r;
        const int gn = n0g + wv * 32 + nf * 16 + l15;
        const float x = acc[mf][nf][r] + b1v[nf];
        const float hval = x / (1.0f + expf(-x));  // silu
        unsigned short hi_, lo_;
        split_bf16(hval, hi_, lo_);
        const size_t o = (size_t)gm * HID + gn;
        hh[o] = hi_;
        hl[o] = lo_;
      }

#undef AHO
#undef ALO
#undef BHO
#undef BLO
}

// ---------------- GEMM2 + normalize/softplus/FK epilogue ------------------------------
__global__ __launch_bounds__(256, 2) void k_gemm2(
    const unsigned short* __restrict__ hh, const unsigned short* __restrict__ hl,
    const unsigned short* __restrict__ w2h, const unsigned short* __restrict__ w2l,
    const float* __restrict__ b2, float* __restrict__ out) {
  __shared__ unsigned short Ah[2][2048], Al[2][2048];  // [64][32]
  __shared__ unsigned short Bh[2][4096], Bl[2][4096];  // [128][32]
  __shared__ float raw[64][97];                        // +1 pad: no stride-96 conflicts

  const int tid = threadIdx.x;
  const int m0 = blockIdx.x * 64;
  const int w = tid >> 6, lane = tid & 63;
  const int wr = w >> 1, wc = w & 1;
  const int l15 = lane & 15, lg = lane >> 4;
  const int arow = tid >> 2, ac8 = (tid & 3) << 3;

  const unsigned short* hhb = hh + (size_t)(m0 + arow) * HID + ac8;
  const unsigned short* hlb = hl + (size_t)(m0 + arow) * HID + ac8;
  const unsigned short* w2hb = w2h + (size_t)arow * HID + ac8;
  const unsigned short* w2lb = w2l + (size_t)arow * HID + ac8;

  f32x4 acc[2][3] = {};

#define G2_STAGE(kt, bf) { \
    gload16(hhb + (kt) * 32, &Ah[bf][(w << 9)]); \
    gload16(hlb + (kt) * 32, &Al[bf][(w << 9)]); \
    gload16(w2hb + (kt) * 32,            &Bh[bf][(w << 9)]); \
    gload16(w2hb + (kt) * 32 + 64 * HID, &Bh[bf][2048 + (w << 9)]); \
    gload16(w2lb + (kt) * 32,            &Bl[bf][(w << 9)]); \
    gload16(w2lb + (kt) * 32 + 64 * HID, &Bl[bf][2048 + (w << 9)]); }

#define G2_COMPUTE(bf) { \
    bf16x8 ah[2], al[2], bh[3], bl[3]; \
    _Pragma("unroll") \
    for (int mf = 0; mf < 2; mf++) { \
      const int o_ = ((wr * 32 + mf * 16 + l15) << 5) + (lg << 3); \
      ah[mf] = ldfrag(&Ah[bf][o_]); \
      al[mf] = ldfrag(&Al[bf][o_]); \
    } \
    _Pragma("unroll") \
    for (int nf = 0; nf < 3; nf++) { \
      const int o_ = ((wc * 48 + nf * 16 + l15) << 5) + (lg << 3); \
      bh[nf] = ldfrag(&Bh[bf][o_]); \
      bl[nf] = ldfrag(&Bl[bf][o_]); \
    } \
    _Pragma("unroll") \
    for (int mf = 0; mf < 2; mf++) { \
      _Pragma("unroll") \
      for (int nf = 0; nf < 3; nf++) { \
        acc[mf][nf] = mfma16(ah[mf], bh[nf], acc[mf][nf]); \
        acc[mf][nf] = mfma16(al[mf], bh[nf], acc[mf][nf]); \
        acc[mf][nf] = mfma16(ah[mf], bl[nf], acc[mf][nf]); \
      } } }

  G2_STAGE(0, 0);
  __syncthreads();
#pragma unroll 2
  for (int kt = 0; kt < 16; kt++) {
    const int cur = kt & 1, nx = cur ^ 1;
    if (kt < 15) G2_STAGE(kt + 1, nx);
    G2_COMPUTE(cur);
    __syncthreads();
  }

  // acc -> raw LDS (raw = h @ W2, no bias yet; cols 92..95 are zero via W2T pad)
#pragma unroll
  for (int mf = 0; mf < 2; mf++) {
#pragma unroll
    for (int nf = 0; nf < 3; nf++) {
#pragma unroll
      for (int r = 0; r < 4; r++) {
        const int ml = wr * 32 + mf * 16 + (lg << 2) + r;
        const int nl = wc * 48 + nf * 16 + l15;
        raw[ml][nl] = acc[mf][nf][r];
      }
    }
  }
  __syncthreads();

  const size_t OFFB = (size_t)BROWS * 72;   // offsets section
  const size_t LENB = (size_t)BROWS * 144;  // length section

  // phase 1: per (row, joint) -> direction*length, write offsets+length, off in-place
  for (int task = tid; task < 64 * 24; task += 256) {
    const int row = task / 24;
    const int j = task - row * 24;
    const int gm = m0 + row;
    float* orow = out + OFFB + (size_t)gm * 72;
    if (j == 0) {
      orow[0] = 0.0f; orow[1] = 0.0f; orow[2] = 0.0f;
    } else {
      const int c0 = (j - 1) * 4;
      const float vx = raw[row][c0 + 0] + b2[c0 + 0];
      const float vy = raw[row][c0 + 1] + b2[c0 + 1];
      const float vz = raw[row][c0 + 2] + b2[c0 + 2];
      const float wv = raw[row][c0 + 3] + b2[c0 + 3];
      const float nrm = sqrtf(vx * vx + vy * vy + vz * vz);
      const float inv = 1.0f / fmaxf(nrm, 1e-12f);
      const float len = fmaxf(wv, 0.0f) + log1pf(expf(-fabsf(wv)));  // softplus
      const float sc = inv * len;
      const float ox = vx * sc, oy = vy * sc, oz = vz * sc;
      orow[j * 3 + 0] = ox; orow[j * 3 + 1] = oy; orow[j * 3 + 2] = oz;
      out[LENB + (size_t)gm * 23 + (j - 1)] = len;
      raw[row][c0 + 0] = ox; raw[row][c0 + 1] = oy; raw[row][c0 + 2] = oz;
    }
  }
  __syncthreads();

  // phase 2: forward kinematics, one thread per row, fully static unroll
  if (tid < 64) {
    constexpr int PAR[24] = {-1, 0, 0, 0, 1, 2, 3, 4, 5, 6, 7, 8,
                             9, 9, 9, 12, 13, 14, 16, 17, 18, 19, 20, 21};
    const int gm = m0 + tid;
    float e[72];
    e[0] = 0.0f; e[1] = 0.0f; e[2] = 0.0f;
#pragma unroll
    for (int j = 1; j < 24; j++) {
      const int p = PAR[j];
      const int c0 = (j - 1) * 4;
      e[3 * j + 0] = e[3 * p + 0] + raw[tid][c0 + 0];
      e[3 * j + 1] = e[3 * p + 1] + raw[tid][c0 + 1];
      e[3 * j + 2] = e[3 * p + 2] + raw[tid][c0 + 2];
    }
    float4* jo = (float4*)(out + (size_t)gm * 72);
#pragma unroll
    for (int q = 0; q < 18; q++)
      jo[q] = make_float4(e[4 * q + 0], e[4 * q + 1], e[4 * q + 2], e[4 * q + 3]);
  }
}

extern "C" void kernel_launch(void* const* d_in, const int* in_sizes, int n_in,
                              void* d_out, int out_size, void* d_ws, size_t ws_size,
                              hipStream_t stream) {
  const float* z = (const float*)d_in[0];
  const float* W1 = (const float*)d_in[1];
  const float* b1 = (const float*)d_in[2];
  const float* W2 = (const float*)d_in[3];
  const float* b2 = (const float*)d_in[4];
  float* out = (float*)d_out;

  char* ws = (char*)d_ws;
  unsigned short* w1h = (unsigned short*)(ws);                                  // 1 MB
  unsigned short* w1l = (unsigned short*)(ws + (1 << 20));                      // 1 MB
  unsigned short* w2h = (unsigned short*)(ws + (2 << 20));                      // 128 KB
  unsigned short* w2l = (unsigned short*)(ws + (2 << 20) + 131072);             // 128 KB
  unsigned short* hh = (unsigned short*)(ws + ((size_t)4 << 20));               // 32 MB
  unsigned short* hl = (unsigned short*)(ws + ((size_t)4 << 20) + ((size_t)32 << 20));  // 32 MB

  hipLaunchKernelGGL(k_prep_w1t, dim3(16, 8), dim3(256), 0, stream, W1, w1h, w1l);
  hipLaunchKernelGGL(k_prep_w2t, dim3(256), dim3(256), 0, stream, W2, w2h, w2l);
  hipLaunchKernelGGL(k_gemm1, dim3(1024), dim3(256), 0, stream, z, w1h, w1l, b1, hh, hl);
  hipLaunchKernelGGL(k_gemm2, dim3(512), dim3(256), 0, stream, hh, hl, w2h, w2l, b2, out);
}

// Round 3
// 151.110 us; speedup vs baseline: 1.1031x; 1.1031x over previous
//
#include <hip/hip_runtime.h>
#include <hip/hip_bf16.h>
#include <stdint.h>

#define BROWS 32768
#define LATENT 1024
#define HID 512

typedef float f32x4 __attribute__((ext_vector_type(4)));
typedef __bf16 bf16x8 __attribute__((ext_vector_type(8)));
typedef unsigned short us8 __attribute__((ext_vector_type(8)));

__device__ __forceinline__ void gload16(const void* g, void* l) {
  __builtin_amdgcn_global_load_lds(
      (__attribute__((address_space(1))) void*)g,
      (__attribute__((address_space(3))) void*)l, 16, 0, 0);
}

// hi/lo bf16 split: x ~= hi + lo, residual ~2^-17 * |x|
__device__ __forceinline__ void split_bf16(float x, unsigned short& hi, unsigned short& lo) {
  __bf16 h = (__bf16)x;
  float r = x - (float)h;
  __bf16 l = (__bf16)r;
  hi = __builtin_bit_cast(unsigned short, h);
  lo = __builtin_bit_cast(unsigned short, l);
}

__device__ __forceinline__ f32x4 mfma16(bf16x8 a, bf16x8 b, f32x4 c) {
  return __builtin_amdgcn_mfma_f32_16x16x32_bf16(a, b, c, 0, 0, 0);
}

__device__ __forceinline__ bf16x8 ldfrag(const void* p) {
  return __builtin_bit_cast(bf16x8, *(const us8*)p);
}

// ---- prep: W1 (1024x512 f32) -> fused swizzled W1F: [n][kt][8 slots of 16B] ----------
// logical slot ls<4: hi bf16 of k = kt*32 + ls*8 .. +8 ; ls>=4: lo of (ls-4) chunk.
// stored at phys slot p = ls ^ (n&7)  (pre-swizzle so gload_lds can be linear).
__global__ __launch_bounds__(256) void k_prep_w1f(const float* __restrict__ W1,
                                                  unsigned short* __restrict__ w1f) {
  const int n = blockIdx.x;   // 0..511
  const int t = threadIdx.x;  // 0..255
  const int kt = t >> 3, ls = t & 7;
  const int p = ls ^ (n & 7);
  const int k0 = kt * 32 + (ls & 3) * 8;
  unsigned short v[8];
#pragma unroll
  for (int e = 0; e < 8; e++) {
    const float x = W1[(size_t)(k0 + e) * HID + n];
    unsigned short h, q;
    split_bf16(x, h, q);
    v[e] = (ls < 4) ? h : q;
  }
  unsigned short* dst = w1f + ((size_t)n * 32 + kt) * 64 + p * 8;
  *(ushort4*)(dst) = make_ushort4(v[0], v[1], v[2], v[3]);
  *(ushort4*)(dst + 4) = make_ushort4(v[4], v[5], v[6], v[7]);
}

// ---------------- prep: W2 (512x92 f32) -> W2T hi/lo bf16 [128][512], rows>=92 zero ----
__global__ __launch_bounds__(256) void k_prep_w2t(const float* __restrict__ W2,
                                                  unsigned short* __restrict__ hi,
                                                  unsigned short* __restrict__ lo) {
  const int idx = blockIdx.x * 256 + threadIdx.x;  // 65536 = 128*512
  const int n = idx >> 9, k = idx & 511;
  const float v = (n < 92) ? W2[(size_t)k * 92 + n] : 0.0f;
  unsigned short h, l;
  split_bf16(v, h, l);
  hi[idx] = h;
  lo[idx] = l;
}

// ---------------- GEMM1: h = silu(z @ W1 + b1) -----------------------------------------
// 256x256 tile, 8 waves, wave-tile 128x64, BK=32, 3 terms (Ah.Bh, Al.Bh, Ah.Bl).
// One barrier per K-tile; counted vmcnt(4) pre-barrier; 128KB dbuf LDS.
// LDS per buf (64KB): A rows [256][128B] @0 ; B rows [256][128B] @32768.
// Row layout 128B = 8 slots of 16B, phys slot = logical ^ (row&7).
__global__ __launch_bounds__(512, 2) void k_gemm1(
    const float* __restrict__ z, const unsigned short* __restrict__ w1f,
    const float* __restrict__ b1,
    unsigned short* __restrict__ hh, unsigned short* __restrict__ hl) {
  extern __shared__ __align__(16) char lb[];

  const int tid = threadIdx.x;
  const int bid = blockIdx.x;
  const int swzb = (bid & 7) * 32 + (bid >> 3);  // bijective XCD swizzle (256 blocks)
  const int mb = swzb >> 1, nbk = swzb & 1;
  const int m0 = mb * 256, n0g = nbk * 256;

  const int wv = tid >> 6, l = tid & 63;
  const int wr = wv >> 2, wc = wv & 3;  // wave grid 2m x 4n
  const int l15 = l & 15, lg = l >> 4;
  const int xr = l15 & 7;

  // frag read byte bases (within a buffer)
  const int ahB = (wr * 128 + l15) * 128 + ((lg ^ xr) << 4);
  const int alB = (wr * 128 + l15) * 128 + ((((4 | lg) ^ xr)) << 4);
  const int bhB = 32768 + (wc * 64 + l15) * 128 + ((lg ^ xr) << 4);
  const int blB = 32768 + (wc * 64 + l15) * 128 + ((((4 | lg) ^ xr)) << 4);

  // A staging: thread handles rows arow+64i, k-chunk kc4 (4 floats)
  const int arow = tid >> 3;
  const int kc4 = tid & 7;
  const int xw = arow & 7;
  const int hi_off = (((kc4 >> 1) ^ xw) << 4) + (kc4 & 1) * 8;
  const int lo_off = ((((4 | (kc4 >> 1)) ^ xw)) << 4) + (kc4 & 1) * 8;
  const float* zb = z + (size_t)(m0 + arow) * LATENT + kc4 * 4;

  // B staging: per-lane global src (layout is pre-swizzled; address is linear)
  const unsigned short* bsrc =
      w1f + ((size_t)(n0g + wv * 32 + (l >> 3)) * 32) * 64 + (l & 7) * 8;

  f32x4 acc[8][4] = {};
  float4 zr[4];

#define LOAD_ZR(kt1)                                                          \
  {                                                                           \
    _Pragma("unroll") for (int i_ = 0; i_ < 4; i_++)                          \
        zr[i_] = *(const float4*)(zb + (size_t)(64 * i_) * LATENT + (kt1) * 32); \
  }

#define WRITE_A(bufo)                                                         \
  {                                                                           \
    _Pragma("unroll") for (int i_ = 0; i_ < 4; i_++) {                        \
      unsigned short h0, h1, h2, h3, q0, q1, q2, q3;                          \
      split_bf16(zr[i_].x, h0, q0); split_bf16(zr[i_].y, h1, q1);             \
      split_bf16(zr[i_].z, h2, q2); split_bf16(zr[i_].w, h3, q3);             \
      char* rp = lb + (bufo) + (arow + 64 * i_) * 128;                        \
      *(ushort4*)(rp + hi_off) = make_ushort4(h0, h1, h2, h3);                \
      *(ushort4*)(rp + lo_off) = make_ushort4(q0, q1, q2, q3);                \
    }                                                                         \
  }

#define GLOAD_B(bufo, kt1)                                                    \
  {                                                                           \
    _Pragma("unroll") for (int j_ = 0; j_ < 4; j_++)                          \
        gload16(bsrc + (size_t)j_ * 16384 + (kt1) * 64,                       \
                lb + (bufo) + 32768 + (wv * 32 + j_ * 8) * 128);              \
  }

#define MCLUSTER(AF, BF)                                                      \
  {                                                                           \
    __builtin_amdgcn_s_setprio(1);                                            \
    _Pragma("unroll") for (int mf = 0; mf < 8; mf++)                          \
        _Pragma("unroll") for (int nf = 0; nf < 4; nf++)                      \
            acc[mf][nf] = mfma16(AF[mf], BF[nf], acc[mf][nf]);                \
    __builtin_amdgcn_s_setprio(0);                                            \
  }

  // ---- prologue: tile 0 into buf0; leave zr(1) in flight ----
  GLOAD_B(0, 0);
  LOAD_ZR(0);
  asm volatile("s_waitcnt vmcnt(0)" ::: "memory");
  WRITE_A(0);
  LOAD_ZR(1);
  asm volatile("s_waitcnt lgkmcnt(0)" ::: "memory");
  __builtin_amdgcn_s_barrier();
  __builtin_amdgcn_sched_barrier(0);

#pragma unroll 2
  for (int t = 0; t < 32; ++t) {
    const int cb = (t & 1) * 65536;
    const int nb2 = cb ^ 65536;

    bf16x8 ah[8], bh[4];
#pragma unroll
    for (int mf = 0; mf < 8; mf++) ah[mf] = ldfrag(lb + cb + ahB + mf * 2048);
#pragma unroll
    for (int nf = 0; nf < 4; nf++) bh[nf] = ldfrag(lb + cb + bhB + nf * 2048);

    if (t < 31) {
      WRITE_A(nb2);        // consumes zr(t+1); compiler inserts the vm wait
      GLOAD_B(nb2, t + 1); // 4 gloads -> in flight across M1..M3
      asm volatile("" ::: "memory");  // pin issue order: B gloads before zr loads
      if (t < 30) LOAD_ZR(t + 2);
    }

    // M1: Ah(t) * Bh(t)
    MCLUSTER(ah, bh);

    // M2: Al(t) * Bh(t)
    {
      bf16x8 alf[8];
#pragma unroll
      for (int mf = 0; mf < 8; mf++) alf[mf] = ldfrag(lb + cb + alB + mf * 2048);
      MCLUSTER(alf, bh);
    }

    // M3: Ah(t) * Bl(t)
    {
      bf16x8 blf[4];
#pragma unroll
      for (int nf = 0; nf < 4; nf++) blf[nf] = ldfrag(lb + cb + blB + nf * 2048);
      MCLUSTER(ah, blf);
    }

    // tile-end: own B(t+1) copies done (zr(t+2) may fly), writes drained, barrier
    if (t < 30) { asm volatile("s_waitcnt vmcnt(4)" ::: "memory"); }
    else        { asm volatile("s_waitcnt vmcnt(0)" ::: "memory"); }
    asm volatile("s_waitcnt lgkmcnt(0)" ::: "memory");
    __builtin_amdgcn_s_barrier();
    __builtin_amdgcn_sched_barrier(0);
  }

  // ---- epilogue: bias + silu + hi/lo split store ----
  float b1v[4];
#pragma unroll
  for (int nf = 0; nf < 4; nf++) b1v[nf] = b1[n0g + wc * 64 + nf * 16 + l15];

#pragma unroll
  for (int mf = 0; mf < 8; mf++)
#pragma unroll
    for (int nf = 0; nf < 4; nf++)
#pragma unroll
      for (int r = 0; r < 4; r++) {
        const int gm = m0 + wr * 128 + mf * 16 + (lg << 2) + r;
        const int gn = n0g + wc * 64 + nf * 16 + l15;
        const float x = acc[mf][nf][r] + b1v[nf];
        const float hval = x / (1.0f + expf(-x));  // silu
        unsigned short hi_, lo_;
        split_bf16(hval, hi_, lo_);
        const size_t o = (size_t)gm * HID + gn;
        hh[o] = hi_;
        hl[o] = lo_;
      }
}

// ---------------- GEMM2 + normalize/softplus/FK epilogue ------------------------------
__global__ __launch_bounds__(256, 2) void k_gemm2(
    const unsigned short* __restrict__ hh, const unsigned short* __restrict__ hl,
    const unsigned short* __restrict__ w2h, const unsigned short* __restrict__ w2l,
    const float* __restrict__ b2, float* __restrict__ out) {
  __shared__ unsigned short Ah[2][2048], Al[2][2048];  // [64][32]
  __shared__ unsigned short Bh[2][4096], Bl[2][4096];  // [128][32]
  __shared__ float raw[64][97];                        // +1 pad: no stride-96 conflicts

  const int tid = threadIdx.x;
  const int m0 = blockIdx.x * 64;
  const int w = tid >> 6, lane = tid & 63;
  const int wr = w >> 1, wc = w & 1;
  const int l15 = lane & 15, lg = lane >> 4;
  const int arow = tid >> 2, ac8 = (tid & 3) << 3;

  const unsigned short* hhb = hh + (size_t)(m0 + arow) * HID + ac8;
  const unsigned short* hlb = hl + (size_t)(m0 + arow) * HID + ac8;
  const unsigned short* w2hb = w2h + (size_t)arow * HID + ac8;
  const unsigned short* w2lb = w2l + (size_t)arow * HID + ac8;

  f32x4 acc[2][3] = {};

#define G2_STAGE(kt, bf) { \
    gload16(hhb + (kt) * 32, &Ah[bf][(w << 9)]); \
    gload16(hlb + (kt) * 32, &Al[bf][(w << 9)]); \
    gload16(w2hb + (kt) * 32,            &Bh[bf][(w << 9)]); \
    gload16(w2hb + (kt) * 32 + 64 * HID, &Bh[bf][2048 + (w << 9)]); \
    gload16(w2lb + (kt) * 32,            &Bl[bf][(w << 9)]); \
    gload16(w2lb + (kt) * 32 + 64 * HID, &Bl[bf][2048 + (w << 9)]); }

#define G2_COMPUTE(bf) { \
    bf16x8 ah2[2], al2[2], bh2[3], bl2[3]; \
    _Pragma("unroll") \
    for (int mf = 0; mf < 2; mf++) { \
      const int o_ = ((wr * 32 + mf * 16 + l15) << 5) + (lg << 3); \
      ah2[mf] = ldfrag(&Ah[bf][o_]); \
      al2[mf] = ldfrag(&Al[bf][o_]); \
    } \
    _Pragma("unroll") \
    for (int nf = 0; nf < 3; nf++) { \
      const int o_ = ((wc * 48 + nf * 16 + l15) << 5) + (lg << 3); \
      bh2[nf] = ldfrag(&Bh[bf][o_]); \
      bl2[nf] = ldfrag(&Bl[bf][o_]); \
    } \
    _Pragma("unroll") \
    for (int mf = 0; mf < 2; mf++) { \
      _Pragma("unroll") \
      for (int nf = 0; nf < 3; nf++) { \
        acc[mf][nf] = mfma16(ah2[mf], bh2[nf], acc[mf][nf]); \
        acc[mf][nf] = mfma16(al2[mf], bh2[nf], acc[mf][nf]); \
        acc[mf][nf] = mfma16(ah2[mf], bl2[nf], acc[mf][nf]); \
      } } }

  G2_STAGE(0, 0);
  __syncthreads();
#pragma unroll 2
  for (int kt = 0; kt < 16; kt++) {
    const int cur = kt & 1, nx = cur ^ 1;
    if (kt < 15) G2_STAGE(kt + 1, nx);
    G2_COMPUTE(cur);
    __syncthreads();
  }

  // acc -> raw LDS (raw = h @ W2, no bias yet; cols 92..95 are zero via W2T pad)
#pragma unroll
  for (int mf = 0; mf < 2; mf++) {
#pragma unroll
    for (int nf = 0; nf < 3; nf++) {
#pragma unroll
      for (int r = 0; r < 4; r++) {
        const int ml = wr * 32 + mf * 16 + (lg << 2) + r;
        const int nl = wc * 48 + nf * 16 + l15;
        raw[ml][nl] = acc[mf][nf][r];
      }
    }
  }
  __syncthreads();

  const size_t OFFB = (size_t)BROWS * 72;   // offsets section
  const size_t LENB = (size_t)BROWS * 144;  // length section

  // phase 1: per (row, joint) -> direction*length, write offsets+length, off in-place
  for (int task = tid; task < 64 * 24; task += 256) {
    const int row = task / 24;
    const int j = task - row * 24;
    const int gm = m0 + row;
    float* orow = out + OFFB + (size_t)gm * 72;
    if (j == 0) {
      orow[0] = 0.0f; orow[1] = 0.0f; orow[2] = 0.0f;
    } else {
      const int c0 = (j - 1) * 4;
      const float vx = raw[row][c0 + 0] + b2[c0 + 0];
      const float vy = raw[row][c0 + 1] + b2[c0 + 1];
      const float vz = raw[row][c0 + 2] + b2[c0 + 2];
      const float wvv = raw[row][c0 + 3] + b2[c0 + 3];
      const float nrm = sqrtf(vx * vx + vy * vy + vz * vz);
      const float inv = 1.0f / fmaxf(nrm, 1e-12f);
      const float len = fmaxf(wvv, 0.0f) + log1pf(expf(-fabsf(wvv)));  // softplus
      const float sc = inv * len;
      const float ox = vx * sc, oy = vy * sc, oz = vz * sc;
      orow[j * 3 + 0] = ox; orow[j * 3 + 1] = oy; orow[j * 3 + 2] = oz;
      out[LENB + (size_t)gm * 23 + (j - 1)] = len;
      raw[row][c0 + 0] = ox; raw[row][c0 + 1] = oy; raw[row][c0 + 2] = oz;
    }
  }
  __syncthreads();

  // phase 2: forward kinematics, one thread per row, fully static unroll
  if (tid < 64) {
    constexpr int PAR[24] = {-1, 0, 0, 0, 1, 2, 3, 4, 5, 6, 7, 8,
                             9, 9, 9, 12, 13, 14, 16, 17, 18, 19, 20, 21};
    const int gm = m0 + tid;
    float e[72];
    e[0] = 0.0f; e[1] = 0.0f; e[2] = 0.0f;
#pragma unroll
    for (int j = 1; j < 24; j++) {
      const int p = PAR[j];
      const int c0 = (j - 1) * 4;
      e[3 * j + 0] = e[3 * p + 0] + raw[tid][c0 + 0];
      e[3 * j + 1] = e[3 * p + 1] + raw[tid][c0 + 1];
      e[3 * j + 2] = e[3 * p + 2] + raw[tid][c0 + 2];
    }
    float4* jo = (float4*)(out + (size_t)gm * 72);
#pragma unroll
    for (int q = 0; q < 18; q++)
      jo[q] = make_float4(e[4 * q + 0], e[4 * q + 1], e[4 * q + 2], e[4 * q + 3]);
  }
}

extern "C" void kernel_launch(void* const* d_in, const int* in_sizes, int n_in,
                              void* d_out, int out_size, void* d_ws, size_t ws_size,
                              hipStream_t stream) {
  const float* z = (const float*)d_in[0];
  const float* W1 = (const float*)d_in[1];
  const float* b1 = (const float*)d_in[2];
  const float* W2 = (const float*)d_in[3];
  const float* b2 = (const float*)d_in[4];
  float* out = (float*)d_out;

  char* ws = (char*)d_ws;
  unsigned short* w1f = (unsigned short*)(ws);                                  // 2 MB
  unsigned short* w2h = (unsigned short*)(ws + (2 << 20));                      // 128 KB
  unsigned short* w2l = (unsigned short*)(ws + (2 << 20) + 131072);             // 128 KB
  unsigned short* hh = (unsigned short*)(ws + ((size_t)4 << 20));               // 32 MB
  unsigned short* hl = (unsigned short*)(ws + ((size_t)4 << 20) + ((size_t)32 << 20));  // 32 MB

  static bool attr_set = false;
  (void)attr_set;
  hipFuncSetAttribute((const void*)k_gemm1,
                      hipFuncAttributeMaxDynamicSharedMemorySize, 131072);

  hipLaunchKernelGGL(k_prep_w1f, dim3(512), dim3(256), 0, stream, W1, w1f);
  hipLaunchKernelGGL(k_prep_w2t, dim3(256), dim3(256), 0, stream, W2, w2h, w2l);
  hipLaunchKernelGGL(k_gemm1, dim3(256), dim3(512), 131072, stream, z, w1f, b1, hh, hl);
  hipLaunchKernelGGL(k_gemm2, dim3(512), dim3(256), 0, stream, hh, hl, w2h, w2l, b2, out);
}

// Round 4
// 147.849 us; speedup vs baseline: 1.1275x; 1.0221x over previous
//
#include <hip/hip_runtime.h>
#include <hip/hip_bf16.h>
#include <stdint.h>

#define BROWS 32768
#define LATENT 1024
#define HID 512

typedef float f32x4 __attribute__((ext_vector_type(4)));
typedef __bf16 bf16x8 __attribute__((ext_vector_type(8)));
typedef unsigned short us8 __attribute__((ext_vector_type(8)));

__device__ __forceinline__ void gload16(const void* g, void* l) {
  __builtin_amdgcn_global_load_lds(
      (__attribute__((address_space(1))) void*)g,
      (__attribute__((address_space(3))) void*)l, 16, 0, 0);
}

// hi/lo bf16 split: x ~= hi + lo, residual ~2^-17 * |x|
__device__ __forceinline__ void split_bf16(float x, unsigned short& hi, unsigned short& lo) {
  __bf16 h = (__bf16)x;
  float r = x - (float)h;
  __bf16 l = (__bf16)r;
  hi = __builtin_bit_cast(unsigned short, h);
  lo = __builtin_bit_cast(unsigned short, l);
}

__device__ __forceinline__ f32x4 mfma16(bf16x8 a, bf16x8 b, f32x4 c) {
  return __builtin_amdgcn_mfma_f32_16x16x32_bf16(a, b, c, 0, 0, 0);
}

__device__ __forceinline__ bf16x8 ldfrag(const void* p) {
  return __builtin_bit_cast(bf16x8, *(const us8*)p);
}

// ---- prep: W1 (1024x512 f32) -> fused swizzled W1F: [n][kt][8 slots of 16B] ----------
// logical slot ls<4: hi bf16 of k = kt*32 + ls*8 .. +8 ; ls>=4: lo of (ls-4) chunk.
// stored at phys slot p = ls ^ (n&7)  (pre-swizzle so gload_lds can be linear).
__global__ __launch_bounds__(256) void k_prep_w1f(const float* __restrict__ W1,
                                                  unsigned short* __restrict__ w1f) {
  const int n = blockIdx.x;   // 0..511
  const int t = threadIdx.x;  // 0..255
  const int kt = t >> 3, ls = t & 7;
  const int p = ls ^ (n & 7);
  const int k0 = kt * 32 + (ls & 3) * 8;
  unsigned short v[8];
#pragma unroll
  for (int e = 0; e < 8; e++) {
    const float x = W1[(size_t)(k0 + e) * HID + n];
    unsigned short h, q;
    split_bf16(x, h, q);
    v[e] = (ls < 4) ? h : q;
  }
  unsigned short* dst = w1f + ((size_t)n * 32 + kt) * 64 + p * 8;
  *(ushort4*)(dst) = make_ushort4(v[0], v[1], v[2], v[3]);
  *(ushort4*)(dst + 4) = make_ushort4(v[4], v[5], v[6], v[7]);
}

// ---------------- prep: W2 (512x92 f32) -> W2T hi/lo bf16 [128][512], rows>=92 zero ----
__global__ __launch_bounds__(256) void k_prep_w2t(const float* __restrict__ W2,
                                                  unsigned short* __restrict__ hi,
                                                  unsigned short* __restrict__ lo) {
  const int idx = blockIdx.x * 256 + threadIdx.x;  // 65536 = 128*512
  const int n = idx >> 9, k = idx & 511;
  const float v = (n < 92) ? W2[(size_t)k * 92 + n] : 0.0f;
  unsigned short h, l;
  split_bf16(v, h, l);
  hi[idx] = h;
  lo[idx] = l;
}

// ---------------- GEMM1: h = silu(z @ W1 + b1) -----------------------------------------
// Tile 128(M)x256(N), BK=32, 4 waves (2m x 2n), wave-tile 64x128. A direct global->reg
// (in-reg hi/lo split, no A LDS). B via LDS dbuf (2x32KB), counted vmcnt ledger:
// per iter in-flight order = [B(t) 8 gloads][A(t) 8 loads] -> vmcnt(8)/vmcnt(8)/vmcnt(0).
// Grid 512 = 2 blocks/CU for cross-block barrier overlap.
__global__ __launch_bounds__(256, 2) void k_gemm1(
    const float* __restrict__ z, const unsigned short* __restrict__ w1f,
    const float* __restrict__ b1,
    unsigned short* __restrict__ hh, unsigned short* __restrict__ hl) {
  extern __shared__ __align__(16) char lb[];

  const int tid = threadIdx.x;
  const int bid = blockIdx.x;
  const int swz = (bid & 7) * 64 + (bid >> 3);  // bijective XCD swizzle (512 blocks)
  const int mb = swz >> 1, nbk = swz & 1;       // (mb, nbk=0/1) adjacent on same XCD
  const int m0 = mb * 128, n0g = nbk * 256;

  const int wv = tid >> 6, l = tid & 63;
  const int wr = wv >> 1, wc = wv & 1;  // wave grid 2m x 2n
  const int l15 = l & 15, lg = l >> 4;
  const int xr = l15 & 7;

  // B frag read byte bases within a buffer (rows = n-local, 128B/row, slot^=(row&7))
  const int bhB = (wc * 128 + l15) * 128 + ((lg ^ xr) << 4);
  const int blB = (wc * 128 + l15) * 128 + ((((4 | lg) ^ xr)) << 4);

  // A direct loads: lane covers z[m0 + wr*64 + mf*16 + l15][kt*32 + lg*8 .. +8]
  const float* zb = z + (size_t)(m0 + wr * 64 + l15) * LATENT + lg * 8;

  // B staging: per-lane global src (pre-swizzled layout; linear LDS dest)
  const unsigned short* bsrc =
      w1f + ((size_t)(n0g + wv * 64 + (l >> 3)) * 32) * 64 + (l & 7) * 8;

  f32x4 acc[4][8] = {};
  float4 arl[4], arh[4];
  bf16x8 ah[4], alo[4];

#define LOAD_A(kt1)                                                           \
  {                                                                           \
    _Pragma("unroll") for (int mf = 0; mf < 4; mf++) {                        \
      const float* p_ = zb + (size_t)(16 * mf) * LATENT + (kt1) * 32;         \
      arl[mf] = *(const float4*)(p_);                                         \
      arh[mf] = *(const float4*)(p_ + 4);                                     \
    }                                                                         \
  }

#define SPLIT_A                                                               \
  {                                                                           \
    _Pragma("unroll") for (int mf = 0; mf < 4; mf++) {                        \
      _Pragma("unroll") for (int e = 0; e < 4; e++) {                         \
        float f0 = arl[mf][e], f1 = arh[mf][e];                               \
        __bf16 h0 = (__bf16)f0, h1 = (__bf16)f1;                              \
        ah[mf][e] = h0;     alo[mf][e] = (__bf16)(f0 - (float)h0);            \
        ah[mf][4 + e] = h1; alo[mf][4 + e] = (__bf16)(f1 - (float)h1);        \
      }                                                                       \
    }                                                                         \
  }

#define GLOAD_B(bufo, kt1)                                                    \
  {                                                                           \
    _Pragma("unroll") for (int j_ = 0; j_ < 8; j_++)                          \
        gload16(bsrc + (size_t)j_ * 16384 + (kt1) * 64,                       \
                lb + (bufo) + (wv * 64 + j_ * 8) * 128);                      \
  }

#define COMPUTE(bufo)                                                         \
  {                                                                           \
    __builtin_amdgcn_s_setprio(1);                                            \
    _Pragma("unroll") for (int nf = 0; nf < 8; nf++) {                        \
      bf16x8 bh = ldfrag(lb + (bufo) + bhB + nf * 2048);                      \
      _Pragma("unroll") for (int mf = 0; mf < 4; mf++)                        \
          acc[mf][nf] = mfma16(ah[mf], bh, acc[mf][nf]);                      \
      _Pragma("unroll") for (int mf = 0; mf < 4; mf++)                        \
          acc[mf][nf] = mfma16(alo[mf], bh, acc[mf][nf]);                     \
    }                                                                         \
    _Pragma("unroll") for (int nf = 0; nf < 8; nf++) {                        \
      bf16x8 bl = ldfrag(lb + (bufo) + blB + nf * 2048);                      \
      _Pragma("unroll") for (int mf = 0; mf < 4; mf++)                        \
          acc[mf][nf] = mfma16(ah[mf], bl, acc[mf][nf]);                      \
    }                                                                         \
    __builtin_amdgcn_s_setprio(0);                                            \
  }

  // ---- prologue: issue B(0) then A(0) ----
  GLOAD_B(0, 0);
  LOAD_A(0);

#pragma unroll 2
  for (int t = 0; t < 32; ++t) {
    const int cb = (t & 1) * 32768;
    const int nb2 = cb ^ 32768;

    asm volatile("s_waitcnt vmcnt(8)" ::: "memory");  // B(t) landed in LDS
    __builtin_amdgcn_s_barrier();                     // all waves have B(t); nxt free

    if (t < 31) {
      GLOAD_B(nb2, t + 1);                            // 8 gloads, newest in ledger
      asm volatile("s_waitcnt vmcnt(8)" ::: "memory");  // A(t) regs landed
    } else {
      asm volatile("s_waitcnt vmcnt(0)" ::: "memory");
    }
    SPLIT_A;                                          // consume A(t) regs
    if (t < 31) LOAD_A(t + 1);                        // reuse arl/arh (WAR ordered)

    COMPUTE(cb);
  }

  // ---- epilogue: bias + silu + hi/lo split store ----
  float b1v[8];
#pragma unroll
  for (int nf = 0; nf < 8; nf++) b1v[nf] = b1[n0g + wc * 128 + nf * 16 + l15];

#pragma unroll
  for (int mf = 0; mf < 4; mf++)
#pragma unroll
    for (int nf = 0; nf < 8; nf++)
#pragma unroll
      for (int r = 0; r < 4; r++) {
        const int gm = m0 + wr * 64 + mf * 16 + (lg << 2) + r;
        const int gn = n0g + wc * 128 + nf * 16 + l15;
        const float x = acc[mf][nf][r] + b1v[nf];
        const float hval = x / (1.0f + expf(-x));  // silu
        unsigned short hi_, lo_;
        split_bf16(hval, hi_, lo_);
        const size_t o = (size_t)gm * HID + gn;
        hh[o] = hi_;
        hl[o] = lo_;
      }
}

// ---------------- GEMM2 + normalize/softplus/FK epilogue ------------------------------
__global__ __launch_bounds__(256, 2) void k_gemm2(
    const unsigned short* __restrict__ hh, const unsigned short* __restrict__ hl,
    const unsigned short* __restrict__ w2h, const unsigned short* __restrict__ w2l,
    const float* __restrict__ b2, float* __restrict__ out) {
  __shared__ unsigned short Ah[2][2048], Al[2][2048];  // [64][32]
  __shared__ unsigned short Bh[2][4096], Bl[2][4096];  // [128][32]
  __shared__ float raw[64][97];                        // +1 pad: no stride-96 conflicts

  const int tid = threadIdx.x;
  const int m0 = blockIdx.x * 64;
  const int w = tid >> 6, lane = tid & 63;
  const int wr = w >> 1, wc = w & 1;
  const int l15 = lane & 15, lg = lane >> 4;
  const int arow = tid >> 2, ac8 = (tid & 3) << 3;

  const unsigned short* hhb = hh + (size_t)(m0 + arow) * HID + ac8;
  const unsigned short* hlb = hl + (size_t)(m0 + arow) * HID + ac8;
  const unsigned short* w2hb = w2h + (size_t)arow * HID + ac8;
  const unsigned short* w2lb = w2l + (size_t)arow * HID + ac8;

  f32x4 acc[2][3] = {};

#define G2_STAGE(kt, bf) { \
    gload16(hhb + (kt) * 32, &Ah[bf][(w << 9)]); \
    gload16(hlb + (kt) * 32, &Al[bf][(w << 9)]); \
    gload16(w2hb + (kt) * 32,            &Bh[bf][(w << 9)]); \
    gload16(w2hb + (kt) * 32 + 64 * HID, &Bh[bf][2048 + (w << 9)]); \
    gload16(w2lb + (kt) * 32,            &Bl[bf][(w << 9)]); \
    gload16(w2lb + (kt) * 32 + 64 * HID, &Bl[bf][2048 + (w << 9)]); }

#define G2_COMPUTE(bf) { \
    bf16x8 ah2[2], al2[2], bh2[3], bl2[3]; \
    _Pragma("unroll") \
    for (int mf = 0; mf < 2; mf++) { \
      const int o_ = ((wr * 32 + mf * 16 + l15) << 5) + (lg << 3); \
      ah2[mf] = ldfrag(&Ah[bf][o_]); \
      al2[mf] = ldfrag(&Al[bf][o_]); \
    } \
    _Pragma("unroll") \
    for (int nf = 0; nf < 3; nf++) { \
      const int o_ = ((wc * 48 + nf * 16 + l15) << 5) + (lg << 3); \
      bh2[nf] = ldfrag(&Bh[bf][o_]); \
      bl2[nf] = ldfrag(&Bl[bf][o_]); \
    } \
    _Pragma("unroll") \
    for (int mf = 0; mf < 2; mf++) { \
      _Pragma("unroll") \
      for (int nf = 0; nf < 3; nf++) { \
        acc[mf][nf] = mfma16(ah2[mf], bh2[nf], acc[mf][nf]); \
        acc[mf][nf] = mfma16(al2[mf], bh2[nf], acc[mf][nf]); \
        acc[mf][nf] = mfma16(ah2[mf], bl2[nf], acc[mf][nf]); \
      } } }

  G2_STAGE(0, 0);
  __syncthreads();
#pragma unroll 2
  for (int kt = 0; kt < 16; kt++) {
    const int cur = kt & 1, nx = cur ^ 1;
    if (kt < 15) G2_STAGE(kt + 1, nx);
    G2_COMPUTE(cur);
    __syncthreads();
  }

  // acc -> raw LDS (raw = h @ W2, no bias yet; cols 92..95 are zero via W2T pad)
#pragma unroll
  for (int mf = 0; mf < 2; mf++) {
#pragma unroll
    for (int nf = 0; nf < 3; nf++) {
#pragma unroll
      for (int r = 0; r < 4; r++) {
        const int ml = wr * 32 + mf * 16 + (lg << 2) + r;
        const int nl = wc * 48 + nf * 16 + l15;
        raw[ml][nl] = acc[mf][nf][r];
      }
    }
  }
  __syncthreads();

  const size_t OFFB = (size_t)BROWS * 72;   // offsets section
  const size_t LENB = (size_t)BROWS * 144;  // length section

  // phase 1: per (row, joint) -> direction*length, write offsets+length, off in-place
  for (int task = tid; task < 64 * 24; task += 256) {
    const int row = task / 24;
    const int j = task - row * 24;
    const int gm = m0 + row;
    float* orow = out + OFFB + (size_t)gm * 72;
    if (j == 0) {
      orow[0] = 0.0f; orow[1] = 0.0f; orow[2] = 0.0f;
    } else {
      const int c0 = (j - 1) * 4;
      const float vx = raw[row][c0 + 0] + b2[c0 + 0];
      const float vy = raw[row][c0 + 1] + b2[c0 + 1];
      const float vz = raw[row][c0 + 2] + b2[c0 + 2];
      const float wvv = raw[row][c0 + 3] + b2[c0 + 3];
      const float nrm = sqrtf(vx * vx + vy * vy + vz * vz);
      const float inv = 1.0f / fmaxf(nrm, 1e-12f);
      const float len = fmaxf(wvv, 0.0f) + log1pf(expf(-fabsf(wvv)));  // softplus
      const float sc = inv * len;
      const float ox = vx * sc, oy = vy * sc, oz = vz * sc;
      orow[j * 3 + 0] = ox; orow[j * 3 + 1] = oy; orow[j * 3 + 2] = oz;
      out[LENB + (size_t)gm * 23 + (j - 1)] = len;
      raw[row][c0 + 0] = ox; raw[row][c0 + 1] = oy; raw[row][c0 + 2] = oz;
    }
  }
  __syncthreads();

  // phase 2: forward kinematics, one thread per row, fully static unroll
  if (tid < 64) {
    constexpr int PAR[24] = {-1, 0, 0, 0, 1, 2, 3, 4, 5, 6, 7, 8,
                             9, 9, 9, 12, 13, 14, 16, 17, 18, 19, 20, 21};
    const int gm = m0 + tid;
    float e[72];
    e[0] = 0.0f; e[1] = 0.0f; e[2] = 0.0f;
#pragma unroll
    for (int j = 1; j < 24; j++) {
      const int p = PAR[j];
      const int c0 = (j - 1) * 4;
      e[3 * j + 0] = e[3 * p + 0] + raw[tid][c0 + 0];
      e[3 * j + 1] = e[3 * p + 1] + raw[tid][c0 + 1];
      e[3 * j + 2] = e[3 * p + 2] + raw[tid][c0 + 2];
    }
    float4* jo = (float4*)(out + (size_t)gm * 72);
#pragma unroll
    for (int q = 0; q < 18; q++)
      jo[q] = make_float4(e[4 * q + 0], e[4 * q + 1], e[4 * q + 2], e[4 * q + 3]);
  }
}

extern "C" void kernel_launch(void* const* d_in, const int* in_sizes, int n_in,
                              void* d_out, int out_size, void* d_ws, size_t ws_size,
                              hipStream_t stream) {
  const float* z = (const float*)d_in[0];
  const float* W1 = (const float*)d_in[1];
  const float* b1 = (const float*)d_in[2];
  const float* W2 = (const float*)d_in[3];
  const float* b2 = (const float*)d_in[4];
  float* out = (float*)d_out;

  char* ws = (char*)d_ws;
  unsigned short* w1f = (unsigned short*)(ws);                                  // 2 MB
  unsigned short* w2h = (unsigned short*)(ws + (2 << 20));                      // 128 KB
  unsigned short* w2l = (unsigned short*)(ws + (2 << 20) + 131072);             // 128 KB
  unsigned short* hh = (unsigned short*)(ws + ((size_t)4 << 20));               // 32 MB
  unsigned short* hl = (unsigned short*)(ws + ((size_t)4 << 20) + ((size_t)32 << 20));  // 32 MB

  hipFuncSetAttribute((const void*)k_gemm1,
                      hipFuncAttributeMaxDynamicSharedMemorySize, 131072);

  hipLaunchKernelGGL(k_prep_w1f, dim3(512), dim3(256), 0, stream, W1, w1f);
  hipLaunchKernelGGL(k_prep_w2t, dim3(256), dim3(256), 0, stream, W2, w2h, w2l);
  hipLaunchKernelGGL(k_gemm1, dim3(512), dim3(256), 65536, stream, z, w1f, b1, hh, hl);
  hipLaunchKernelGGL(k_gemm2, dim3(512), dim3(256), 0, stream, hh, hl, w2h, w2l, b2, out);
}